// Round 5
// baseline (78.901 us; speedup 1.0000x reference)
//
#include <hip/hip_runtime.h>

#define BT 256           // 4 waves per block
#define WREG 13312       // per-wave LDS region bytes
// A-area: 64 rows x 144 B (72 shorts: 48 bf16 obs + 16 zero-pad K, 8 unused)
// ro-area: 64 rows x 208 B (52 f32) -- overlays A-area after MFMA

typedef __attribute__((ext_vector_type(8))) short short8;
typedef __attribute__((ext_vector_type(4))) float f32x4;
typedef __attribute__((ext_vector_type(4))) unsigned int u32x4;
typedef _Float16 h2 __attribute__((ext_vector_type(2)));   // packed fp16 pair

__device__ inline h2 hfma2(h2 a, h2 b, h2 c) { return __builtin_elementwise_fma(a, b, c); }
__device__ inline h2 hmax2(h2 a, h2 b)       { return __builtin_elementwise_max(a, b); }
__device__ inline h2 mkh2(float a, float b)  { h2 r; r[0] = (_Float16)a; r[1] = (_Float16)b; return r; }

// bf16 round-to-nearest-even on raw bits (finite inputs)
__device__ inline unsigned bf16r(float x) {
    unsigned u = __builtin_bit_cast(unsigned, x);
    return (u + 0x7FFFu + ((u >> 16) & 1u)) >> 16;
}
__device__ inline unsigned pk2bf(float a, float b) {
    return bf16r(a) | (bf16r(b) << 16);
}
__device__ inline float b2f(short s) {
    unsigned u = ((unsigned)(unsigned short)s) << 16;
    return __builtin_bit_cast(float, u);
}

// ---- prep: PhiW (48x48 f32, row-major) -> bf16 [48][64], K zero-padded ----
__global__ void prep_kernel(const float* __restrict__ PhiW,
                            unsigned short* __restrict__ wb) {
    int idx = blockIdx.x * 256 + threadIdx.x;   // 0..3071
    if (idx >= 48 * 64) return;
    int j = idx >> 6, k = idx & 63;
    float v = (k < 48) ? PhiW[j * 48 + k] : 0.0f;
    wb[idx] = (unsigned short)bf16r(v);
}

__global__ __launch_bounds__(BT, 3) void vin_kernel(
    const float* __restrict__ obs,
    const unsigned short* __restrict__ wb,   // bf16 PhiW [48][64]
    const float* __restrict__ Phib,
    const float* __restrict__ LW,
    const float* __restrict__ Lb,
    float* __restrict__ out, int Btot)
{
    __shared__ __align__(16) char smem[4 * WREG];   // 53248 B -> 3 blocks/CU
    const int tid  = threadIdx.x;
    const int lane = tid & 63;
    const int wid  = tid >> 6;
    const int b    = blockIdx.x * BT + tid;
    // Btot % 64 == 0, waves entirely in or out; no barriers -> early return safe
    if (b >= Btot) return;

    char* wbase = smem + wid * WREG;
    const int jn = lane & 15;
    const int g  = lane >> 4;

    // ---- load obs row (48 f32, 12x float4, coalesced) ----
    float o[48];
    {
        const float4* g4 = reinterpret_cast<const float4*>(obs + (size_t)b * 48);
        #pragma unroll
        for (int q = 0; q < 12; ++q) {
            float4 t = g4[q];
            o[4*q+0] = t.x; o[4*q+1] = t.y; o[4*q+2] = t.z; o[4*q+3] = t.w;
        }
    }

    // ---- agent index: channel 1 is exactly one-hot (values exactly 1.0f) ----
    float ssum = o[1], sidx = 0.0f;
    #pragma unroll
    for (int k = 1; k < 16; ++k) {
        ssum += o[k*3 + 1];
        sidx = fmaf(o[k*3 + 1], (float)k, sidx);
    }
    const int idx = (ssum != 0.0f) ? (int)(sidx + 0.5f) : 5;
    const int ai = idx >> 2;
    const int aj = idx & 3;

    // ---- B-fragments straight from prepped bf16 ws (L1/L2-hot) ----
    // B[k][j]=PhiW[j*48+k]; lane holds col j=16n+jn, k=32t+8g+e
    short8 bfrag[3][2];
    #pragma unroll
    for (int n = 0; n < 3; ++n)
        #pragma unroll
        for (int t = 0; t < 2; ++t)
            bfrag[n][t] = *reinterpret_cast<const short8*>(
                wb + (16*n + jn) * 64 + 32*t + 8*g);

    // ---- write own obs row to A-area as bf16 (paired cvt), K-pad to 64 ----
    {
        u32x4* arow = reinterpret_cast<u32x4*>(wbase + lane * 144);
        #pragma unroll
        for (int q = 0; q < 6; ++q) {
            u32x4 v;
            #pragma unroll
            for (int e = 0; e < 4; ++e)
                v[e] = pk2bf(o[q*8 + 2*e], o[q*8 + 2*e + 1]);
            arow[q] = v;
        }
        u32x4 z = {0u, 0u, 0u, 0u};
        arow[6] = z; arow[7] = z;   // k = 48..63 zeros
    }

    // ---- sub_state gather (features 0..26) from own bf16 row ----
    float lg0 = Lb[0], lg1 = Lb[1], lg2 = Lb[2], lg3 = Lb[3];
    {
        const short* myobs = reinterpret_cast<const short*>(wbase + lane * 144);
        #pragma unroll
        for (int dh = 0; dh < 3; ++dh)
            #pragma unroll
            for (int dw = 0; dw < 3; ++dw) {
                int r = ai + dh - 1, c = aj + dw - 1;
                bool ok = ((unsigned)r < 4u) && ((unsigned)c < 4u);
                int ba = ok ? (r*4 + c) * 3 : 0;
                float s0 = b2f(myobs[ba+0]);
                float s1 = b2f(myobs[ba+1]);
                float s2 = b2f(myobs[ba+2]);
                if (!ok) { s0 = 0.f; s1 = 0.f; s2 = 0.f; }
                int f = (dh*3 + dw) * 3;
                lg0 = fmaf(s0, LW[0*36+f], fmaf(s1, LW[0*36+f+1], fmaf(s2, LW[0*36+f+2], lg0)));
                lg1 = fmaf(s0, LW[1*36+f], fmaf(s1, LW[1*36+f+1], fmaf(s2, LW[1*36+f+2], lg1)));
                lg2 = fmaf(s0, LW[2*36+f], fmaf(s1, LW[2*36+f+1], fmaf(s2, LW[2*36+f+2], lg2)));
                lg3 = fmaf(s0, LW[3*36+f], fmaf(s1, LW[3*36+f+1], fmaf(s2, LW[3*36+f+2], lg3)));
            }
    }

    // ---- A-fragments: lane reads row m*16+jn, k = 32t+8g..+7 ----
    short8 afrag[4][2];
    #pragma unroll
    for (int m = 0; m < 4; ++m) {
        const char* rp = wbase + (m*16 + jn) * 144;
        afrag[m][0] = *reinterpret_cast<const short8*>(rp + 16*g);
        afrag[m][1] = *reinterpret_cast<const short8*>(rp + 64 + 16*g);
    }

    // ---- 24 MFMAs, bias folded into C-init (bias per col j=16n+jn) ----
    f32x4 acc[4][3];
    {
        float b0 = Phib[jn], b1 = Phib[16 + jn], b2 = Phib[32 + jn];
        #pragma unroll
        for (int m = 0; m < 4; ++m) {
            acc[m][0] = (f32x4){b0, b0, b0, b0};
            acc[m][1] = (f32x4){b1, b1, b1, b1};
            acc[m][2] = (f32x4){b2, b2, b2, b2};
        }
    }
    #pragma unroll
    for (int n = 0; n < 3; ++n)
        #pragma unroll
        for (int m = 0; m < 4; ++m) {
            acc[m][n] = __builtin_amdgcn_mfma_f32_16x16x32_bf16(afrag[m][0], bfrag[n][0], acc[m][n], 0, 0, 0);
            acc[m][n] = __builtin_amdgcn_mfma_f32_16x16x32_bf16(afrag[m][1], bfrag[n][1], acc[m][n], 0, 0, 0);
        }

    // A-area ds_reads complete before ro-area writes overwrite the overlay
    asm volatile("s_waitcnt lgkmcnt(0)" ::: "memory");
    __builtin_amdgcn_sched_barrier(0);

    // ---- scatter D: lane holds col 16n+jn, rows m*16+g*4+r ----
    #pragma unroll
    for (int m = 0; m < 4; ++m)
        #pragma unroll
        for (int n = 0; n < 3; ++n)
            #pragma unroll
            for (int r = 0; r < 4; ++r) {
                int row = m*16 + g*4 + r;
                reinterpret_cast<float*>(wbase + row * 208)[n*16 + jn] = acc[m][n][r];
            }

    asm volatile("s_waitcnt lgkmcnt(0)" ::: "memory");
    __builtin_amdgcn_sched_barrier(0);

    // ---- read back own ro row (48 f32, bias already included) ----
    float ro[48];
    {
        const char* myrow = wbase + lane * 208;
        #pragma unroll
        for (int q = 0; q < 12; ++q) {
            f32x4 t = *reinterpret_cast<const f32x4*>(myrow + q * 16);
            ro[4*q+0] = t[0]; ro[4*q+1] = t[1]; ro[4*q+2] = t[2]; ro[4*q+3] = t[3];
        }
    }

    // ---- VI constants (f32), then pack to fp16 pairs (cl, cl+2) ----
    float pcf[16], aLf[16], aRf[16], aUf[16], aDf[16];
    #pragma unroll
    for (int h = 0; h < 4; ++h)
        #pragma unroll
        for (int w = 0; w < 4; ++w) {
            int cl = h*4 + w;
            float rout = ro[cl*3 + 1];
            pcf[cl] = ro[cl*3 + 2];
            aLf[cl] = ((w > 0) ? ro[(cl-1)*3] : 0.0f) - rout;
            aRf[cl] = ((w < 3) ? ro[(cl+1)*3] : 0.0f) - rout;
            aUf[cl] = ((h > 0) ? ro[(cl-4)*3] : 0.0f) - rout;
            aDf[cl] = ((h < 3) ? ro[(cl+4)*3] : 0.0f) - rout;
        }

    h2 p2[4][2], aL2[4][2], aR2[4][2], aU2[4][2], aD2[4][2];
    #pragma unroll
    for (int h = 0; h < 4; ++h)
        #pragma unroll
        for (int j = 0; j < 2; ++j) {
            int c0 = h*4 + j, c1 = h*4 + j + 2;
            p2[h][j]  = mkh2(pcf[c0], pcf[c1]);
            aL2[h][j] = mkh2(aLf[c0], aLf[c1]);
            aR2[h][j] = mkh2(aRf[c0], aRf[c1]);
            aU2[h][j] = mkh2(aUf[c0], aUf[c1]);
            aD2[h][j] = mkh2(aDf[c0], aDf[c1]);
        }

    // ---- K=20 VI steps in packed fp16 ----
    // pack (h,j): lo = V[h][j], hi = V[h][j+2]
    // L-nb of (h,0) = (bnd, V[h][1]) = Vp[h][1] << 16 (zero shifts in = boundary)
    // L-nb of (h,1) = Vp[h][0]; R-nb of (h,0) = Vp[h][1]
    // R-nb of (h,1) = (V[h][2], bnd) = Vp[h][0] >> 16
    h2 Vp[4][2];
    #pragma unroll
    for (int h = 0; h < 4; ++h) {
        Vp[h][0] = mkh2(0.f, 0.f);
        Vp[h][1] = mkh2(0.f, 0.f);
    }

    #pragma unroll 1
    for (int s = 0; s < 20; ++s) {
        h2 shl[4], shr[4], Vn[4][2];
        #pragma unroll
        for (int h = 0; h < 4; ++h) {
            shl[h] = __builtin_bit_cast(h2, __builtin_bit_cast(unsigned, Vp[h][1]) << 16);
            shr[h] = __builtin_bit_cast(h2, __builtin_bit_cast(unsigned, Vp[h][0]) >> 16);
        }
        #pragma unroll
        for (int h = 0; h < 4; ++h)
            #pragma unroll
            for (int j = 0; j < 2; ++j) {
                h2 vL = j ? Vp[h][0] : shl[h];
                h2 vR = j ? shr[h] : Vp[h][1];
                h2 tU = (h > 0) ? hfma2(p2[h][j], Vp[h-1][j], aU2[h][j]) : aU2[h][j];
                h2 tD = (h < 3) ? hfma2(p2[h][j], Vp[h+1][j], aD2[h][j]) : aD2[h][j];
                h2 m1 = hmax2(Vp[h][j], hfma2(p2[h][j], vL, aL2[h][j]));
                h2 m2 = hmax2(hfma2(p2[h][j], vR, aR2[h][j]), tU);
                Vn[h][j] = hmax2(hmax2(m1, m2), tD);
            }
        #pragma unroll
        for (int h = 0; h < 4; ++h) { Vp[h][0] = Vn[h][0]; Vp[h][1] = Vn[h][1]; }
    }

    // ---- unpack V, store to own ro row words 0..15, dynamic 3x3 gather ----
    {
        char* myrow = wbase + lane * 208;
        #pragma unroll
        for (int h = 0; h < 4; ++h) {
            float v0 = (float)Vp[h][0][0];
            float v1 = (float)Vp[h][1][0];
            float v2 = (float)Vp[h][0][1];
            float v3 = (float)Vp[h][1][1];
            *reinterpret_cast<f32x4*>(myrow + h * 16) = (f32x4){v0, v1, v2, v3};
        }
    }
    asm volatile("s_waitcnt lgkmcnt(0)" ::: "memory");
    __builtin_amdgcn_sched_barrier(0);
    {
        const float* myv = reinterpret_cast<const float*>(wbase + lane * 208);
        #pragma unroll
        for (int dh = 0; dh < 3; ++dh)
            #pragma unroll
            for (int dw = 0; dw < 3; ++dw) {
                int r = ai + dh - 1, c = aj + dw - 1;
                bool ok = ((unsigned)r < 4u) && ((unsigned)c < 4u);
                int ba = ok ? (r*4 + c) : 0;
                float v = myv[ba];
                if (!ok) v = 0.0f;
                int f = 27 + dh*3 + dw;
                lg0 = fmaf(v, LW[0*36+f], lg0);
                lg1 = fmaf(v, LW[1*36+f], lg1);
                lg2 = fmaf(v, LW[2*36+f], lg2);
                lg3 = fmaf(v, LW[3*36+f], lg3);
            }
    }

    reinterpret_cast<float4*>(out)[b] = make_float4(lg0, lg1, lg2, lg3);
}

extern "C" void kernel_launch(void* const* d_in, const int* in_sizes, int n_in,
                              void* d_out, int out_size, void* d_ws, size_t ws_size,
                              hipStream_t stream) {
    const float* obs  = (const float*)d_in[0];
    const float* PhiW = (const float*)d_in[1];
    const float* Phib = (const float*)d_in[2];
    const float* LW   = (const float*)d_in[3];
    const float* Lb   = (const float*)d_in[4];
    float* out = (float*)d_out;
    unsigned short* wb = (unsigned short*)d_ws;   // 6144 B bf16 PhiW

    hipLaunchKernelGGL(prep_kernel, dim3(12), dim3(256), 0, stream, PhiW, wb);

    const int Btot = in_sizes[0] / 48;   // 1,000,000
    const int grid = (Btot + BT - 1) / BT;
    hipLaunchKernelGGL(vin_kernel, dim3(grid), dim3(BT), 0, stream,
                       obs, wb, Phib, LW, Lb, out, Btot);
}

// Round 7
// 75.945 us; speedup vs baseline: 1.0389x; 1.0389x over previous
//
#include <hip/hip_runtime.h>

#define BT 256           // 4 waves per block
#define WREG 13312       // per-wave LDS region bytes
// A-area: 64 rows x 144 B (72 shorts: 48 bf16 obs + 16 zero-pad K, 8 unused)
// ro-area: 64 rows x 208 B (52 f32) -- overlays A-area after MFMA

typedef __attribute__((ext_vector_type(8))) short short8;
typedef __attribute__((ext_vector_type(4))) float f32x4;
typedef __attribute__((ext_vector_type(4))) unsigned int u32x4;
typedef _Float16 h2 __attribute__((ext_vector_type(2)));

// bf16 round-to-nearest-even on raw bits (finite inputs)
__device__ inline unsigned bf16r(float x) {
    unsigned u = __builtin_bit_cast(unsigned, x);
    return (u + 0x7FFFu + ((u >> 16) & 1u)) >> 16;
}
__device__ inline unsigned pk2bf(float a, float b) {
    return bf16r(a) | (bf16r(b) << 16);
}
__device__ inline float b2f(short s) {
    unsigned u = ((unsigned)(unsigned short)s) << 16;
    return __builtin_bit_cast(float, u);
}
// pack two f32 -> two f16 (RTZ), single instruction, result as raw u32
__device__ inline unsigned pkrtz(float a, float b) {
    unsigned d;
    asm("v_cvt_pkrtz_f16_f32 %0, %1, %2" : "=v"(d) : "v"(a), "v"(b));
    return d;
}
// guaranteed-packed f16 ops (VOP3P)
__device__ inline unsigned pkfma(unsigned a, unsigned b, unsigned c) {
    unsigned d;
    asm("v_pk_fma_f16 %0, %1, %2, %3" : "=v"(d) : "v"(a), "v"(b), "v"(c));
    return d;
}
__device__ inline unsigned pkmax(unsigned a, unsigned b) {
    unsigned d;
    asm("v_pk_max_f16 %0, %1, %2" : "=v"(d) : "v"(a), "v"(b));
    return d;
}

__global__ __launch_bounds__(BT, 3) void vin_kernel(
    const float* __restrict__ obs,
    const float* __restrict__ PhiW,
    const float* __restrict__ Phib,
    const float* __restrict__ LW,
    const float* __restrict__ Lb,
    float* __restrict__ out, int Btot)
{
    __shared__ __align__(16) char smem[4 * WREG];   // 53248 B -> 3 blocks/CU
    const int tid  = threadIdx.x;
    const int lane = tid & 63;
    const int wid  = tid >> 6;
    const int b    = blockIdx.x * BT + tid;
    // Btot % 64 == 0, waves entirely in or out; no barriers -> early return safe
    if (b >= Btot) return;

    char* wbase = smem + wid * WREG;
    const int jn = lane & 15;
    const int g  = lane >> 4;

    // ---- load obs row (48 f32, 12x float4, coalesced) ----
    float o[48];
    {
        const float4* g4 = reinterpret_cast<const float4*>(obs + (size_t)b * 48);
        #pragma unroll
        for (int q = 0; q < 12; ++q) {
            float4 t = g4[q];
            o[4*q+0] = t.x; o[4*q+1] = t.y; o[4*q+2] = t.z; o[4*q+3] = t.w;
        }
    }

    // ---- agent index: channel 1 is exactly one-hot (values exactly 1.0f) ----
    float ssum = o[1], sidx = 0.0f;
    #pragma unroll
    for (int k = 1; k < 16; ++k) {
        ssum += o[k*3 + 1];
        sidx = fmaf(o[k*3 + 1], (float)k, sidx);
    }
    const int idx = (ssum != 0.0f) ? (int)(sidx + 0.5f) : 5;
    const int ai = idx >> 2;
    const int aj = idx & 3;

    // ---- B-fragments: PhiW^T tiles straight from global (L2-hot), bf16 ----
    // B[k][j] = PhiW[j*48+k]; lane holds col j=16n+jn, k = kbase + g*8 .. +7
    short8 bfrag[3][2];
    #pragma unroll
    for (int n = 0; n < 3; ++n) {
        const float* wrow = PhiW + (16*n + jn) * 48;
        float4 q0 = *reinterpret_cast<const float4*>(wrow + 8*g);
        float4 q1 = *reinterpret_cast<const float4*>(wrow + 8*g + 4);
        u32x4 t0;
        t0[0] = pk2bf(q0.x, q0.y); t0[1] = pk2bf(q0.z, q0.w);
        t0[2] = pk2bf(q1.x, q1.y); t0[3] = pk2bf(q1.z, q1.w);
        bfrag[n][0] = __builtin_bit_cast(short8, t0);
        u32x4 tz = {0u, 0u, 0u, 0u};
        if (g < 2) {   // k = 32+8g..+7 valid only for g<2; k>=48 zero pad
            float4 q2 = *reinterpret_cast<const float4*>(wrow + 32 + 8*g);
            float4 q3 = *reinterpret_cast<const float4*>(wrow + 36 + 8*g);
            tz[0] = pk2bf(q2.x, q2.y); tz[1] = pk2bf(q2.z, q2.w);
            tz[2] = pk2bf(q3.x, q3.y); tz[3] = pk2bf(q3.z, q3.w);
        }
        bfrag[n][1] = __builtin_bit_cast(short8, tz);
    }

    // ---- write own obs row to A-area as bf16 (paired pack), K-pad to 64 ----
    {
        u32x4* arow = reinterpret_cast<u32x4*>(wbase + lane * 144);
        #pragma unroll
        for (int q = 0; q < 6; ++q) {
            u32x4 v;
            #pragma unroll
            for (int e = 0; e < 4; ++e)
                v[e] = pk2bf(o[q*8 + 2*e], o[q*8 + 2*e + 1]);
            arow[q] = v;
        }
        u32x4 z = {0u, 0u, 0u, 0u};
        arow[6] = z; arow[7] = z;   // k = 48..63 zeros
    }

    // ---- sub_state gather (features 0..26) from own bf16 row ----
    float lg0 = Lb[0], lg1 = Lb[1], lg2 = Lb[2], lg3 = Lb[3];
    {
        const short* myobs = reinterpret_cast<const short*>(wbase + lane * 144);
        #pragma unroll
        for (int dh = 0; dh < 3; ++dh)
            #pragma unroll
            for (int dw = 0; dw < 3; ++dw) {
                int r = ai + dh - 1, c = aj + dw - 1;
                bool ok = ((unsigned)r < 4u) && ((unsigned)c < 4u);
                int ba = ok ? (r*4 + c) * 3 : 0;
                float s0 = b2f(myobs[ba+0]);
                float s1 = b2f(myobs[ba+1]);
                float s2 = b2f(myobs[ba+2]);
                if (!ok) { s0 = 0.f; s1 = 0.f; s2 = 0.f; }
                int f = (dh*3 + dw) * 3;
                lg0 = fmaf(s0, LW[0*36+f], fmaf(s1, LW[0*36+f+1], fmaf(s2, LW[0*36+f+2], lg0)));
                lg1 = fmaf(s0, LW[1*36+f], fmaf(s1, LW[1*36+f+1], fmaf(s2, LW[1*36+f+2], lg1)));
                lg2 = fmaf(s0, LW[2*36+f], fmaf(s1, LW[2*36+f+1], fmaf(s2, LW[2*36+f+2], lg2)));
                lg3 = fmaf(s0, LW[3*36+f], fmaf(s1, LW[3*36+f+1], fmaf(s2, LW[3*36+f+2], lg3)));
            }
    }

    // ---- A-fragments: lane reads row m*16+jn, k = 32t+8g..+7 ----
    short8 afrag[4][2];
    #pragma unroll
    for (int m = 0; m < 4; ++m) {
        const char* rp = wbase + (m*16 + jn) * 144;
        afrag[m][0] = *reinterpret_cast<const short8*>(rp + 16*g);
        afrag[m][1] = *reinterpret_cast<const short8*>(rp + 64 + 16*g);
    }

    // ---- 24 MFMAs, bias folded into C-init (bias per col j=16n+jn) ----
    f32x4 acc[4][3];
    {
        float b0 = Phib[jn], b1 = Phib[16 + jn], b2 = Phib[32 + jn];
        #pragma unroll
        for (int m = 0; m < 4; ++m) {
            acc[m][0] = (f32x4){b0, b0, b0, b0};
            acc[m][1] = (f32x4){b1, b1, b1, b1};
            acc[m][2] = (f32x4){b2, b2, b2, b2};
        }
    }
    #pragma unroll
    for (int n = 0; n < 3; ++n)
        #pragma unroll
        for (int m = 0; m < 4; ++m) {
            acc[m][n] = __builtin_amdgcn_mfma_f32_16x16x32_bf16(afrag[m][0], bfrag[n][0], acc[m][n], 0, 0, 0);
            acc[m][n] = __builtin_amdgcn_mfma_f32_16x16x32_bf16(afrag[m][1], bfrag[n][1], acc[m][n], 0, 0, 0);
        }

    // A-area ds_reads complete before ro-area writes overwrite the overlay
    asm volatile("s_waitcnt lgkmcnt(0)" ::: "memory");
    __builtin_amdgcn_sched_barrier(0);

    // ---- scatter D: lane holds col 16n+jn, rows m*16+g*4+r ----
    #pragma unroll
    for (int m = 0; m < 4; ++m)
        #pragma unroll
        for (int n = 0; n < 3; ++n)
            #pragma unroll
            for (int r = 0; r < 4; ++r) {
                int row = m*16 + g*4 + r;
                reinterpret_cast<float*>(wbase + row * 208)[n*16 + jn] = acc[m][n][r];
            }

    asm volatile("s_waitcnt lgkmcnt(0)" ::: "memory");
    __builtin_amdgcn_sched_barrier(0);

    // ---- read back own ro row (48 f32, bias already included) ----
    float ro[48];
    {
        const char* myrow = wbase + lane * 208;
        #pragma unroll
        for (int q = 0; q < 12; ++q) {
            f32x4 t = *reinterpret_cast<const f32x4*>(myrow + q * 16);
            ro[4*q+0] = t[0]; ro[4*q+1] = t[1]; ro[4*q+2] = t[2]; ro[4*q+3] = t[3];
        }
    }

    // ---- VI constants (f32 subs), packed to f16 pairs (cl, cl+2) via pkrtz ----
    float pcf[16], aLf[16], aRf[16], aUf[16], aDf[16];
    #pragma unroll
    for (int h = 0; h < 4; ++h)
        #pragma unroll
        for (int w = 0; w < 4; ++w) {
            int cl = h*4 + w;
            float rout = ro[cl*3 + 1];
            pcf[cl] = ro[cl*3 + 2];
            aLf[cl] = ((w > 0) ? ro[(cl-1)*3] : 0.0f) - rout;
            aRf[cl] = ((w < 3) ? ro[(cl+1)*3] : 0.0f) - rout;
            aUf[cl] = ((h > 0) ? ro[(cl-4)*3] : 0.0f) - rout;
            aDf[cl] = ((h < 3) ? ro[(cl+4)*3] : 0.0f) - rout;
        }

    unsigned p2[4][2], aL2[4][2], aR2[4][2], aU2[4][2], aD2[4][2];
    #pragma unroll
    for (int h = 0; h < 4; ++h)
        #pragma unroll
        for (int j = 0; j < 2; ++j) {
            int c0 = h*4 + j, c1 = h*4 + j + 2;
            p2[h][j]  = pkrtz(pcf[c0], pcf[c1]);
            aL2[h][j] = pkrtz(aLf[c0], aLf[c1]);
            aR2[h][j] = pkrtz(aRf[c0], aRf[c1]);
            aU2[h][j] = pkrtz(aUf[c0], aUf[c1]);
            aD2[h][j] = pkrtz(aDf[c0], aDf[c1]);
        }

    // ---- K=20 VI steps, packed f16 via VOP3P inline asm ----
    // pack (h,j): lo = V[h][j], hi = V[h][j+2]
    // L-nb of (h,0)-pack = (bnd, V[h][1]) = Vp[h][1] << 16 (zero = boundary)
    // L-nb of (h,1)-pack = Vp[h][0]; R-nb of (h,0)-pack = Vp[h][1]
    // R-nb of (h,1)-pack = (V[h][2], bnd) = Vp[h][0] >> 16
    unsigned Vp[4][2];
    #pragma unroll
    for (int h = 0; h < 4; ++h) { Vp[h][0] = 0u; Vp[h][1] = 0u; }

    #pragma unroll 1
    for (int s = 0; s < 20; ++s) {
        unsigned shl[4], shr[4], Vn[4][2];
        #pragma unroll
        for (int h = 0; h < 4; ++h) {
            shl[h] = Vp[h][1] << 16;
            shr[h] = Vp[h][0] >> 16;
        }
        #pragma unroll
        for (int h = 0; h < 4; ++h)
            #pragma unroll
            for (int j = 0; j < 2; ++j) {
                unsigned vL = j ? Vp[h][0] : shl[h];
                unsigned vR = j ? shr[h] : Vp[h][1];
                unsigned tU = (h > 0) ? pkfma(p2[h][j], Vp[h-1][j], aU2[h][j]) : aU2[h][j];
                unsigned tD = (h < 3) ? pkfma(p2[h][j], Vp[h+1][j], aD2[h][j]) : aD2[h][j];
                unsigned m1 = pkmax(Vp[h][j], pkfma(p2[h][j], vL, aL2[h][j]));
                unsigned m2 = pkmax(pkfma(p2[h][j], vR, aR2[h][j]), tU);
                Vn[h][j] = pkmax(pkmax(m1, m2), tD);
            }
        #pragma unroll
        for (int h = 0; h < 4; ++h) { Vp[h][0] = Vn[h][0]; Vp[h][1] = Vn[h][1]; }
    }

    // ---- unpack V, store to own ro row words 0..15, dynamic 3x3 gather ----
    {
        char* myrow = wbase + lane * 208;
        #pragma unroll
        for (int h = 0; h < 4; ++h) {
            h2 a = __builtin_bit_cast(h2, Vp[h][0]);
            h2 c = __builtin_bit_cast(h2, Vp[h][1]);
            *reinterpret_cast<f32x4*>(myrow + h * 16) =
                (f32x4){(float)a[0], (float)c[0], (float)a[1], (float)c[1]};
        }
    }
    asm volatile("s_waitcnt lgkmcnt(0)" ::: "memory");
    __builtin_amdgcn_sched_barrier(0);
    {
        const float* myv = reinterpret_cast<const float*>(wbase + lane * 208);
        #pragma unroll
        for (int dh = 0; dh < 3; ++dh)
            #pragma unroll
            for (int dw = 0; dw < 3; ++dw) {
                int r = ai + dh - 1, c = aj + dw - 1;
                bool ok = ((unsigned)r < 4u) && ((unsigned)c < 4u);
                int ba = ok ? (r*4 + c) : 0;
                float v = myv[ba];
                if (!ok) v = 0.0f;
                int f = 27 + dh*3 + dw;
                lg0 = fmaf(v, LW[0*36+f], lg0);
                lg1 = fmaf(v, LW[1*36+f], lg1);
                lg2 = fmaf(v, LW[2*36+f], lg2);
                lg3 = fmaf(v, LW[3*36+f], lg3);
            }
    }

    reinterpret_cast<float4*>(out)[b] = make_float4(lg0, lg1, lg2, lg3);
}

extern "C" void kernel_launch(void* const* d_in, const int* in_sizes, int n_in,
                              void* d_out, int out_size, void* d_ws, size_t ws_size,
                              hipStream_t stream) {
    const float* obs  = (const float*)d_in[0];
    const float* PhiW = (const float*)d_in[1];
    const float* Phib = (const float*)d_in[2];
    const float* LW   = (const float*)d_in[3];
    const float* Lb   = (const float*)d_in[4];
    float* out = (float*)d_out;

    const int Btot = in_sizes[0] / 48;   // 1,000,000
    const int grid = (Btot + BT - 1) / BT;
    hipLaunchKernelGGL(vin_kernel, dim3(grid), dim3(BT), 0, stream,
                       obs, PhiW, Phib, LW, Lb, out, Btot);
}

// Round 8
// 70.409 us; speedup vs baseline: 1.1206x; 1.0786x over previous
//
#include <hip/hip_runtime.h>

#define BT 256           // 4 waves per block
#define WREG 13312       // per-wave LDS region bytes
// A-area: 64 rows x 144 B (72 shorts: 48 bf16 obs + 16 zero-pad K, 8 unused)
// ro-area: 64 rows x 208 B (52 f32) -- overlays A-area after MFMA

typedef __attribute__((ext_vector_type(8))) short short8;
typedef __attribute__((ext_vector_type(4))) float f32x4;
typedef __attribute__((ext_vector_type(4))) unsigned int u32x4;
typedef _Float16 h2 __attribute__((ext_vector_type(2)));

// pack two f32 -> two bf16 (RNE), single VOP3 instruction (no builtin on gfx950)
__device__ inline unsigned cvtpkbf(float a, float b) {
    unsigned d;
    asm("v_cvt_pk_bf16_f32 %0, %1, %2" : "=v"(d) : "v"(a), "v"(b));
    return d;
}
__device__ inline float b2f(short s) {
    unsigned u = ((unsigned)(unsigned short)s) << 16;
    return __builtin_bit_cast(float, u);
}
// pack two f32 -> two f16 (RTZ), single instruction, result as raw u32
__device__ inline unsigned pkrtz(float a, float b) {
    unsigned d;
    asm("v_cvt_pkrtz_f16_f32 %0, %1, %2" : "=v"(d) : "v"(a), "v"(b));
    return d;
}
// guaranteed-packed f16 ops (VOP3P)
__device__ inline unsigned pkfma(unsigned a, unsigned b, unsigned c) {
    unsigned d;
    asm("v_pk_fma_f16 %0, %1, %2, %3" : "=v"(d) : "v"(a), "v"(b), "v"(c));
    return d;
}
__device__ inline unsigned pkmax(unsigned a, unsigned b) {
    unsigned d;
    asm("v_pk_max_f16 %0, %1, %2" : "=v"(d) : "v"(a), "v"(b));
    return d;
}

__global__ __launch_bounds__(BT, 3) void vin_kernel(
    const float* __restrict__ obs,
    const float* __restrict__ PhiW,
    const float* __restrict__ Phib,
    const float* __restrict__ LW,
    const float* __restrict__ Lb,
    float* __restrict__ out, int Btot)
{
    __shared__ __align__(16) char smem[4 * WREG];   // 53248 B -> 3 blocks/CU
    const int tid  = threadIdx.x;
    const int lane = tid & 63;
    const int wid  = tid >> 6;
    const int b    = blockIdx.x * BT + tid;
    // Btot % 64 == 0, waves entirely in or out; no barriers -> early return safe
    if (b >= Btot) return;

    char* wbase = smem + wid * WREG;
    const int jn = lane & 15;
    const int g  = lane >> 4;

    // ---- load obs row (48 f32, 12x float4, coalesced) ----
    float o[48];
    {
        const float4* g4 = reinterpret_cast<const float4*>(obs + (size_t)b * 48);
        #pragma unroll
        for (int q = 0; q < 12; ++q) {
            float4 t = g4[q];
            o[4*q+0] = t.x; o[4*q+1] = t.y; o[4*q+2] = t.z; o[4*q+3] = t.w;
        }
    }

    // ---- agent index: channel 1 is exactly one-hot (values exactly 1.0f) ----
    float ssum = o[1], sidx = 0.0f;
    #pragma unroll
    for (int k = 1; k < 16; ++k) {
        ssum += o[k*3 + 1];
        sidx = fmaf(o[k*3 + 1], (float)k, sidx);
    }
    const int idx = (ssum != 0.0f) ? (int)(sidx + 0.5f) : 5;
    const int ai = idx >> 2;
    const int aj = idx & 3;

    // ---- B-fragments: PhiW^T tiles straight from global (L2-hot), bf16 ----
    // B[k][j] = PhiW[j*48+k]; lane holds col j=16n+jn, k = kbase + g*8 .. +7
    short8 bfrag[3][2];
    #pragma unroll
    for (int n = 0; n < 3; ++n) {
        const float* wrow = PhiW + (16*n + jn) * 48;
        float4 q0 = *reinterpret_cast<const float4*>(wrow + 8*g);
        float4 q1 = *reinterpret_cast<const float4*>(wrow + 8*g + 4);
        u32x4 t0;
        t0[0] = cvtpkbf(q0.x, q0.y); t0[1] = cvtpkbf(q0.z, q0.w);
        t0[2] = cvtpkbf(q1.x, q1.y); t0[3] = cvtpkbf(q1.z, q1.w);
        bfrag[n][0] = __builtin_bit_cast(short8, t0);
        u32x4 tz = {0u, 0u, 0u, 0u};
        if (g < 2) {   // k = 32+8g..+7 valid only for g<2; k>=48 zero pad
            float4 q2 = *reinterpret_cast<const float4*>(wrow + 32 + 8*g);
            float4 q3 = *reinterpret_cast<const float4*>(wrow + 36 + 8*g);
            tz[0] = cvtpkbf(q2.x, q2.y); tz[1] = cvtpkbf(q2.z, q2.w);
            tz[2] = cvtpkbf(q3.x, q3.y); tz[3] = cvtpkbf(q3.z, q3.w);
        }
        bfrag[n][1] = __builtin_bit_cast(short8, tz);
    }

    // ---- write own obs row to A-area as bf16 (packed cvt), K-pad to 64 ----
    {
        u32x4* arow = reinterpret_cast<u32x4*>(wbase + lane * 144);
        #pragma unroll
        for (int q = 0; q < 6; ++q) {
            u32x4 v;
            #pragma unroll
            for (int e = 0; e < 4; ++e)
                v[e] = cvtpkbf(o[q*8 + 2*e], o[q*8 + 2*e + 1]);
            arow[q] = v;
        }
        u32x4 z = {0u, 0u, 0u, 0u};
        arow[6] = z; arow[7] = z;   // shorts 48..63 zero (K-pad + gather sentinel)
    }

    // ---- sub_state gather (features 0..26) from own bf16 row ----
    // OOB windows read the zero-pad at shorts 48..50 (sentinel) - no value masks.
    float lg0 = Lb[0], lg1 = Lb[1], lg2 = Lb[2], lg3 = Lb[3];
    {
        const short* myobs = reinterpret_cast<const short*>(wbase + lane * 144);
        #pragma unroll
        for (int dh = 0; dh < 3; ++dh)
            #pragma unroll
            for (int dw = 0; dw < 3; ++dw) {
                int r = ai + dh - 1, c = aj + dw - 1;
                bool ok = ((unsigned)r < 4u) && ((unsigned)c < 4u);
                int ba = ok ? (r*4 + c) * 3 : 48;
                float s0 = b2f(myobs[ba+0]);
                float s1 = b2f(myobs[ba+1]);
                float s2 = b2f(myobs[ba+2]);
                int f = (dh*3 + dw) * 3;
                lg0 = fmaf(s0, LW[0*36+f], fmaf(s1, LW[0*36+f+1], fmaf(s2, LW[0*36+f+2], lg0)));
                lg1 = fmaf(s0, LW[1*36+f], fmaf(s1, LW[1*36+f+1], fmaf(s2, LW[1*36+f+2], lg1)));
                lg2 = fmaf(s0, LW[2*36+f], fmaf(s1, LW[2*36+f+1], fmaf(s2, LW[2*36+f+2], lg2)));
                lg3 = fmaf(s0, LW[3*36+f], fmaf(s1, LW[3*36+f+1], fmaf(s2, LW[3*36+f+2], lg3)));
            }
    }

    // ---- A-fragments: lane reads row m*16+jn, k = 32t+8g..+7 ----
    short8 afrag[4][2];
    #pragma unroll
    for (int m = 0; m < 4; ++m) {
        const char* rp = wbase + (m*16 + jn) * 144;
        afrag[m][0] = *reinterpret_cast<const short8*>(rp + 16*g);
        afrag[m][1] = *reinterpret_cast<const short8*>(rp + 64 + 16*g);
    }

    // ---- 24 MFMAs, bias folded into C-init (bias per col j=16n+jn) ----
    f32x4 acc[4][3];
    {
        float b0 = Phib[jn], b1 = Phib[16 + jn], b2 = Phib[32 + jn];
        #pragma unroll
        for (int m = 0; m < 4; ++m) {
            acc[m][0] = (f32x4){b0, b0, b0, b0};
            acc[m][1] = (f32x4){b1, b1, b1, b1};
            acc[m][2] = (f32x4){b2, b2, b2, b2};
        }
    }
    #pragma unroll
    for (int n = 0; n < 3; ++n)
        #pragma unroll
        for (int m = 0; m < 4; ++m) {
            acc[m][n] = __builtin_amdgcn_mfma_f32_16x16x32_bf16(afrag[m][0], bfrag[n][0], acc[m][n], 0, 0, 0);
            acc[m][n] = __builtin_amdgcn_mfma_f32_16x16x32_bf16(afrag[m][1], bfrag[n][1], acc[m][n], 0, 0, 0);
        }

    // A-area ds_reads complete before ro-area writes overwrite the overlay
    asm volatile("s_waitcnt lgkmcnt(0)" ::: "memory");
    __builtin_amdgcn_sched_barrier(0);

    // ---- scatter D: lane holds col 16n+jn, rows m*16+g*4+r ----
    #pragma unroll
    for (int m = 0; m < 4; ++m)
        #pragma unroll
        for (int n = 0; n < 3; ++n)
            #pragma unroll
            for (int r = 0; r < 4; ++r) {
                int row = m*16 + g*4 + r;
                reinterpret_cast<float*>(wbase + row * 208)[n*16 + jn] = acc[m][n][r];
            }

    asm volatile("s_waitcnt lgkmcnt(0)" ::: "memory");
    __builtin_amdgcn_sched_barrier(0);

    // ---- read back own ro row (48 f32, bias already included) ----
    float ro[48];
    {
        const char* myrow = wbase + lane * 208;
        #pragma unroll
        for (int q = 0; q < 12; ++q) {
            f32x4 t = *reinterpret_cast<const f32x4*>(myrow + q * 16);
            ro[4*q+0] = t[0]; ro[4*q+1] = t[1]; ro[4*q+2] = t[2]; ro[4*q+3] = t[3];
        }
    }

    // ---- VI constants (f32 subs), packed to f16 pairs (cl, cl+2) via pkrtz ----
    float pcf[16], aLf[16], aRf[16], aUf[16], aDf[16];
    #pragma unroll
    for (int h = 0; h < 4; ++h)
        #pragma unroll
        for (int w = 0; w < 4; ++w) {
            int cl = h*4 + w;
            float rout = ro[cl*3 + 1];
            pcf[cl] = ro[cl*3 + 2];
            aLf[cl] = ((w > 0) ? ro[(cl-1)*3] : 0.0f) - rout;
            aRf[cl] = ((w < 3) ? ro[(cl+1)*3] : 0.0f) - rout;
            aUf[cl] = ((h > 0) ? ro[(cl-4)*3] : 0.0f) - rout;
            aDf[cl] = ((h < 3) ? ro[(cl+4)*3] : 0.0f) - rout;
        }

    unsigned p2[4][2], aL2[4][2], aR2[4][2], aU2[4][2], aD2[4][2];
    #pragma unroll
    for (int h = 0; h < 4; ++h)
        #pragma unroll
        for (int j = 0; j < 2; ++j) {
            int c0 = h*4 + j, c1 = h*4 + j + 2;
            p2[h][j]  = pkrtz(pcf[c0], pcf[c1]);
            aL2[h][j] = pkrtz(aLf[c0], aLf[c1]);
            aR2[h][j] = pkrtz(aRf[c0], aRf[c1]);
            aU2[h][j] = pkrtz(aUf[c0], aUf[c1]);
            aD2[h][j] = pkrtz(aDf[c0], aDf[c1]);
        }

    // ---- K=20 VI steps, packed f16 via VOP3P inline asm ----
    // pack (h,j): lo = V[h][j], hi = V[h][j+2]
    // L-nb of (h,0)-pack = (bnd, V[h][1]) = Vp[h][1] << 16 (zero = boundary)
    // L-nb of (h,1)-pack = Vp[h][0]; R-nb of (h,0)-pack = Vp[h][1]
    // R-nb of (h,1)-pack = (V[h][2], bnd) = Vp[h][0] >> 16
    unsigned Vp[4][2];
    #pragma unroll
    for (int h = 0; h < 4; ++h) { Vp[h][0] = 0u; Vp[h][1] = 0u; }

    #pragma unroll 1
    for (int s = 0; s < 20; ++s) {
        unsigned shl[4], shr[4], Vn[4][2];
        #pragma unroll
        for (int h = 0; h < 4; ++h) {
            shl[h] = Vp[h][1] << 16;
            shr[h] = Vp[h][0] >> 16;
        }
        #pragma unroll
        for (int h = 0; h < 4; ++h)
            #pragma unroll
            for (int j = 0; j < 2; ++j) {
                unsigned vL = j ? Vp[h][0] : shl[h];
                unsigned vR = j ? shr[h] : Vp[h][1];
                unsigned tU = (h > 0) ? pkfma(p2[h][j], Vp[h-1][j], aU2[h][j]) : aU2[h][j];
                unsigned tD = (h < 3) ? pkfma(p2[h][j], Vp[h+1][j], aD2[h][j]) : aD2[h][j];
                unsigned m1 = pkmax(Vp[h][j], pkfma(p2[h][j], vL, aL2[h][j]));
                unsigned m2 = pkmax(pkfma(p2[h][j], vR, aR2[h][j]), tU);
                Vn[h][j] = pkmax(pkmax(m1, m2), tD);
            }
        #pragma unroll
        for (int h = 0; h < 4; ++h) { Vp[h][0] = Vn[h][0]; Vp[h][1] = Vn[h][1]; }
    }

    // ---- unpack V, store to own ro row words 0..15 (+zero sentinel at 16) ----
    {
        char* myrow = wbase + lane * 208;
        #pragma unroll
        for (int h = 0; h < 4; ++h) {
            h2 a = __builtin_bit_cast(h2, Vp[h][0]);
            h2 c = __builtin_bit_cast(h2, Vp[h][1]);
            *reinterpret_cast<f32x4*>(myrow + h * 16) =
                (f32x4){(float)a[0], (float)c[0], (float)a[1], (float)c[1]};
        }
        *reinterpret_cast<float*>(myrow + 64) = 0.0f;   // word 16: gather sentinel
    }
    asm volatile("s_waitcnt lgkmcnt(0)" ::: "memory");
    __builtin_amdgcn_sched_barrier(0);
    {
        const float* myv = reinterpret_cast<const float*>(wbase + lane * 208);
        #pragma unroll
        for (int dh = 0; dh < 3; ++dh)
            #pragma unroll
            for (int dw = 0; dw < 3; ++dw) {
                int r = ai + dh - 1, c = aj + dw - 1;
                bool ok = ((unsigned)r < 4u) && ((unsigned)c < 4u);
                int ba = ok ? (r*4 + c) : 16;   // 16 -> zero sentinel
                float v = myv[ba];
                int f = 27 + dh*3 + dw;
                lg0 = fmaf(v, LW[0*36+f], lg0);
                lg1 = fmaf(v, LW[1*36+f], lg1);
                lg2 = fmaf(v, LW[2*36+f], lg2);
                lg3 = fmaf(v, LW[3*36+f], lg3);
            }
    }

    reinterpret_cast<float4*>(out)[b] = make_float4(lg0, lg1, lg2, lg3);
}

extern "C" void kernel_launch(void* const* d_in, const int* in_sizes, int n_in,
                              void* d_out, int out_size, void* d_ws, size_t ws_size,
                              hipStream_t stream) {
    const float* obs  = (const float*)d_in[0];
    const float* PhiW = (const float*)d_in[1];
    const float* Phib = (const float*)d_in[2];
    const float* LW   = (const float*)d_in[3];
    const float* Lb   = (const float*)d_in[4];
    float* out = (float*)d_out;

    const int Btot = in_sizes[0] / 48;   // 1,000,000
    const int grid = (Btot + BT - 1) / BT;
    hipLaunchKernelGGL(vin_kernel, dim3(grid), dim3(BT), 0, stream,
                       obs, PhiW, Phib, LW, Lb, out, Btot);
}